// Round 1
// baseline (88.760 us; speedup 1.0000x reference)
//
#include <hip/hip_runtime.h>
#include <math.h>

#define N_NODES 768
#define N_EDGES 12288
#define D_INF 6
#define H 256
#define NV 4   // nodes per block in layer2
#define TI 3   // rows per block in pair kernel

// ---------------- degree count ----------------
__global__ void k_deg(const int* __restrict__ dst, int* __restrict__ cnt) {
    int e = blockIdx.x * blockDim.x + threadIdx.x;
    if (e < N_EDGES) atomicAdd(&cnt[dst[e]], 1);
}

// ---------------- scan: offsets, cursor, dinv ----------------
__global__ __launch_bounds__(768) void k_scan(const int* __restrict__ cnt,
                                              int* __restrict__ off,
                                              int* __restrict__ pos,
                                              float* __restrict__ dinv) {
    __shared__ int s[N_NODES];
    int t = threadIdx.x;
    int c = cnt[t];
    s[t] = c;
    __syncthreads();
    for (int o = 1; o < N_NODES; o <<= 1) {
        int v = (t >= o) ? s[t - o] : 0;
        __syncthreads();
        s[t] += v;
        __syncthreads();
    }
    int excl = s[t] - c;           // exclusive prefix
    off[t] = excl;
    pos[t] = excl;
    dinv[t] = 1.0f / sqrtf((float)(c + 1));   // +1 self-loop
}

// ---------------- scatter edges into CSR-by-dst ----------------
__global__ void k_scatter(const int* __restrict__ src, const int* __restrict__ dst,
                          const float* __restrict__ dinv, int* __restrict__ pos,
                          int* __restrict__ csr_src, float* __restrict__ csr_w) {
    int e = blockIdx.x * blockDim.x + threadIdx.x;
    if (e >= N_EDGES) return;
    int sI = src[e], dI = dst[e];
    int p = atomicAdd(&pos[dI], 1);
    csr_src[p] = sI;
    csr_w[p] = dinv[sI] * dinv[dI];
}

// ---------------- layer1: h1 = elu( (A x) Wc1 + bc1 ) ----------------
__global__ __launch_bounds__(256) void k_layer1(
    const float* __restrict__ x, const float* __restrict__ Wc1,
    const float* __restrict__ bc1, const int* __restrict__ off,
    const int* __restrict__ cnt, const float* __restrict__ dinv,
    const int* __restrict__ csr_src, const float* __restrict__ csr_w,
    float* __restrict__ h1) {
    int v = blockIdx.x;
    int t = threadIdx.x;
    __shared__ float agg6[D_INF];
    int base = off[v], c = cnt[v];
    float dv = dinv[v];
    if (t < 64) {   // one wave aggregates x
        float a[D_INF] = {0.f, 0.f, 0.f, 0.f, 0.f, 0.f};
        if (t == 0) {
            float w = dv * dv;     // self-loop
            #pragma unroll
            for (int k = 0; k < D_INF; ++k) a[k] = w * x[v * D_INF + k];
        }
        for (int n = t; n < c; n += 64) {
            int s = csr_src[base + n];
            float w = csr_w[base + n];
            #pragma unroll
            for (int k = 0; k < D_INF; ++k) a[k] = fmaf(w, x[s * D_INF + k], a[k]);
        }
        #pragma unroll
        for (int m = 32; m >= 1; m >>= 1) {
            #pragma unroll
            for (int k = 0; k < D_INF; ++k) a[k] += __shfl_xor(a[k], m, 64);
        }
        if (t == 0) {
            #pragma unroll
            for (int k = 0; k < D_INF; ++k) agg6[k] = a[k];
        }
    }
    __syncthreads();
    float acc = bc1[t];
    #pragma unroll
    for (int k = 0; k < D_INF; ++k) acc = fmaf(agg6[k], Wc1[k * H + t], acc);
    h1[v * H + t] = (acc > 0.f) ? acc : expm1f(acc);   // elu
}

// ---------------- layer2 fused: h2 = (A h1) Wc2 + bc2 ; ai = h2 We1a ; ajc = h2 We1b + be1 ----------------
__global__ __launch_bounds__(256) void k_layer2(
    const float* __restrict__ h1, const float* __restrict__ Wc2,
    const float* __restrict__ bc2, const float* __restrict__ We1,
    const float* __restrict__ be1, const int* __restrict__ off,
    const int* __restrict__ cnt, const float* __restrict__ dinv,
    const int* __restrict__ csr_src, const float* __restrict__ csr_w,
    float* __restrict__ aib, float* __restrict__ ajc) {
    int t = threadIdx.x;
    int v0 = blockIdx.x * NV;
    __shared__ __align__(16) float agghT[H][NV];   // transposed for float4 broadcast
    __shared__ __align__(16) float h2sT[H][NV];

    // stage 1: aggregate h1 for NV nodes
    float ag[NV];
    #pragma unroll
    for (int i = 0; i < NV; ++i) {
        int v = v0 + i;
        int base = off[v], c = cnt[v];
        float dv = dinv[v];
        float acc = dv * dv * h1[v * H + t];     // self-loop
        for (int n = 0; n < c; ++n) {
            int s = csr_src[base + n];
            float w = csr_w[base + n];
            acc = fmaf(w, h1[s * H + t], acc);
        }
        ag[i] = acc;
    }
    #pragma unroll
    for (int i = 0; i < NV; ++i) agghT[t][i] = ag[i];
    __syncthreads();

    // stage 2: h2 row = agg @ Wc2 + bc2
    float bb = bc2[t];
    float a0 = bb, a1 = bb, a2 = bb, a3 = bb;
    #pragma unroll 4
    for (int k = 0; k < H; ++k) {
        float wc = Wc2[k * H + t];
        float4 g = *(const float4*)&agghT[k][0];
        a0 = fmaf(g.x, wc, a0); a1 = fmaf(g.y, wc, a1);
        a2 = fmaf(g.z, wc, a2); a3 = fmaf(g.w, wc, a3);
    }
    h2sT[t][0] = a0; h2sT[t][1] = a1; h2sT[t][2] = a2; h2sT[t][3] = a3;
    __syncthreads();

    // stage 3: ai = h2 @ We1[:H], aj = h2 @ We1[H:] (+be1)
    float pi0 = 0.f, pi1 = 0.f, pi2 = 0.f, pi3 = 0.f;
    float pj0 = 0.f, pj1 = 0.f, pj2 = 0.f, pj3 = 0.f;
    #pragma unroll 4
    for (int k = 0; k < H; ++k) {
        float wa = We1[k * H + t];
        float wb = We1[(H + k) * H + t];
        float4 g = *(const float4*)&h2sT[k][0];
        pi0 = fmaf(g.x, wa, pi0); pi1 = fmaf(g.y, wa, pi1);
        pi2 = fmaf(g.z, wa, pi2); pi3 = fmaf(g.w, wa, pi3);
        pj0 = fmaf(g.x, wb, pj0); pj1 = fmaf(g.y, wb, pj1);
        pj2 = fmaf(g.z, wb, pj2); pj3 = fmaf(g.w, wb, pj3);
    }
    float be = be1[t];
    aib[(v0 + 0) * H + t] = pi0;
    aib[(v0 + 1) * H + t] = pi1;
    aib[(v0 + 2) * H + t] = pi2;
    aib[(v0 + 3) * H + t] = pi3;
    ajc[(v0 + 0) * H + t] = pj0 + be;
    ajc[(v0 + 1) * H + t] = pj1 + be;
    ajc[(v0 + 2) * H + t] = pj2 + be;
    ajc[(v0 + 3) * H + t] = pj3 + be;
}

// ---------------- pair + fused row softmax ----------------
// logits[i,j] = sum_h relu(ai[i,h] + ajc[j,h]) * w2[h]   (be2/temp dropped: softmax-invariant)
__global__ __launch_bounds__(256) void k_pair(
    const float* __restrict__ aib, const float* __restrict__ ajc,
    const float* __restrict__ We2, float* __restrict__ out) {
    int t = threadIdx.x;
    int i0 = blockIdx.x * TI;
    __shared__ __align__(16) float s_ai[TI][H];
    __shared__ __align__(16) float s_w2[H];
    __shared__ float red[TI][256];

    s_w2[t] = We2[t];
    #pragma unroll
    for (int i = 0; i < TI; ++i) s_ai[i][t] = aib[(i0 + i) * H + t];
    __syncthreads();

    float acc[TI][3];
    #pragma unroll
    for (int i = 0; i < TI; ++i)
        #pragma unroll
        for (int jj = 0; jj < 3; ++jj) acc[i][jj] = 0.f;

    const float4* A0 = (const float4*)(ajc + (size_t)(t)       * H);
    const float4* A1 = (const float4*)(ajc + (size_t)(t + 256) * H);
    const float4* A2 = (const float4*)(ajc + (size_t)(t + 512) * H);

    #pragma unroll 2
    for (int h4 = 0; h4 < H / 4; ++h4) {
        float4 w = *(const float4*)&s_w2[h4 * 4];
        float4 av0 = *(const float4*)&s_ai[0][h4 * 4];
        float4 av1 = *(const float4*)&s_ai[1][h4 * 4];
        float4 av2 = *(const float4*)&s_ai[2][h4 * 4];
        float4 b0 = A0[h4], b1 = A1[h4], b2 = A2[h4];
        #define STEP(AV, I)                                                    \
            acc[I][0] = fmaf(fmaxf(AV.x + b0.x, 0.f), w.x, acc[I][0]);         \
            acc[I][0] = fmaf(fmaxf(AV.y + b0.y, 0.f), w.y, acc[I][0]);         \
            acc[I][0] = fmaf(fmaxf(AV.z + b0.z, 0.f), w.z, acc[I][0]);         \
            acc[I][0] = fmaf(fmaxf(AV.w + b0.w, 0.f), w.w, acc[I][0]);         \
            acc[I][1] = fmaf(fmaxf(AV.x + b1.x, 0.f), w.x, acc[I][1]);         \
            acc[I][1] = fmaf(fmaxf(AV.y + b1.y, 0.f), w.y, acc[I][1]);         \
            acc[I][1] = fmaf(fmaxf(AV.z + b1.z, 0.f), w.z, acc[I][1]);         \
            acc[I][1] = fmaf(fmaxf(AV.w + b1.w, 0.f), w.w, acc[I][1]);         \
            acc[I][2] = fmaf(fmaxf(AV.x + b2.x, 0.f), w.x, acc[I][2]);         \
            acc[I][2] = fmaf(fmaxf(AV.y + b2.y, 0.f), w.y, acc[I][2]);         \
            acc[I][2] = fmaf(fmaxf(AV.z + b2.z, 0.f), w.z, acc[I][2]);         \
            acc[I][2] = fmaf(fmaxf(AV.w + b2.w, 0.f), w.w, acc[I][2]);
        STEP(av0, 0)
        STEP(av1, 1)
        STEP(av2, 2)
        #undef STEP
    }

    // mask diagonal
    #pragma unroll
    for (int i = 0; i < TI; ++i) {
        int row = i0 + i;
        #pragma unroll
        for (int jj = 0; jj < 3; ++jj)
            if (t + jj * 256 == row) acc[i][jj] = -INFINITY;
    }

    // row max
    #pragma unroll
    for (int i = 0; i < TI; ++i)
        red[i][t] = fmaxf(fmaxf(acc[i][0], acc[i][1]), acc[i][2]);
    __syncthreads();
    for (int s = 128; s > 0; s >>= 1) {
        if (t < s) {
            #pragma unroll
            for (int i = 0; i < TI; ++i)
                red[i][t] = fmaxf(red[i][t], red[i][t + s]);
        }
        __syncthreads();
    }
    float mx[TI];
    #pragma unroll
    for (int i = 0; i < TI; ++i) mx[i] = red[i][0];
    __syncthreads();

    // exp + row sum
    float e[TI][3];
    #pragma unroll
    for (int i = 0; i < TI; ++i) {
        float s0 = 0.f;
        #pragma unroll
        for (int jj = 0; jj < 3; ++jj) {
            e[i][jj] = __expf(acc[i][jj] - mx[i]);
            s0 += e[i][jj];
        }
        red[i][t] = s0;
    }
    __syncthreads();
    for (int s = 128; s > 0; s >>= 1) {
        if (t < s) {
            #pragma unroll
            for (int i = 0; i < TI; ++i)
                red[i][t] += red[i][t + s];
        }
        __syncthreads();
    }
    #pragma unroll
    for (int i = 0; i < TI; ++i) {
        float inv = 1.0f / red[i][0];
        #pragma unroll
        for (int jj = 0; jj < 3; ++jj)
            out[(size_t)(i0 + i) * N_NODES + t + jj * 256] = e[i][jj] * inv;
    }
}

extern "C" void kernel_launch(void* const* d_in, const int* in_sizes, int n_in,
                              void* d_out, int out_size, void* d_ws, size_t ws_size,
                              hipStream_t stream) {
    const float* x   = (const float*)d_in[0];
    const int*   ei  = (const int*)d_in[1];
    const float* Wc1 = (const float*)d_in[2];
    const float* bc1 = (const float*)d_in[3];
    const float* Wc2 = (const float*)d_in[4];
    const float* bc2 = (const float*)d_in[5];
    const float* We1 = (const float*)d_in[6];
    const float* be1 = (const float*)d_in[7];
    const float* We2 = (const float*)d_in[8];
    // be2 (d_in[9]) intentionally unused: softmax is shift-invariant.
    float* out = (float*)d_out;

    char* ws = (char*)d_ws;
    int*   cnt     = (int*)(ws + 0);
    int*   off     = (int*)(ws + 3072);
    int*   pos     = (int*)(ws + 6144);
    float* dinv    = (float*)(ws + 9216);
    int*   csr_src = (int*)(ws + 12288);
    float* csr_w   = (float*)(ws + 61440);
    float* h1      = (float*)(ws + 110592);
    float* aib     = (float*)(ws + 897024);
    float* ajc     = (float*)(ws + 1683456);

    const int* srcA = ei;             // edge_index[0]
    const int* dstA = ei + N_EDGES;   // edge_index[1]

    hipMemsetAsync(cnt, 0, N_NODES * sizeof(int), stream);
    k_deg<<<N_EDGES / 256, 256, 0, stream>>>(dstA, cnt);
    k_scan<<<1, 768, 0, stream>>>(cnt, off, pos, dinv);
    k_scatter<<<N_EDGES / 256, 256, 0, stream>>>(srcA, dstA, dinv, pos, csr_src, csr_w);
    k_layer1<<<N_NODES, 256, 0, stream>>>(x, Wc1, bc1, off, cnt, dinv, csr_src, csr_w, h1);
    k_layer2<<<N_NODES / NV, 256, 0, stream>>>(h1, Wc2, bc2, We1, be1, off, cnt, dinv,
                                               csr_src, csr_w, aib, ajc);
    k_pair<<<N_NODES / TI, 256, 0, stream>>>(aib, ajc, We2, out);
}

// Round 2
// 71.782 us; speedup vs baseline: 1.2365x; 1.2365x over previous
//
#include <hip/hip_runtime.h>
#include <math.h>

#define N_NODES 768
#define N_EDGES 12288
#define D_INF 6
#define H 256
#define RO 3   // rows per block in k_out
#define TI 3   // rows per block in pair kernel

// ---------------- graph prep: degree + scan + scatter, one block ----------------
__global__ __launch_bounds__(512) void k_prep(
    const int* __restrict__ src, const int* __restrict__ dst,
    int* __restrict__ cnt_g, int* __restrict__ off_g, float* __restrict__ dinv_g,
    int* __restrict__ csr_src, float* __restrict__ csr_w) {
    __shared__ int s_cnt[N_NODES];
    __shared__ int s_off[N_NODES];
    __shared__ float s_dinv[N_NODES];
    __shared__ int s_blk[256];
    int t = threadIdx.x;

    for (int v = t; v < N_NODES; v += 512) s_cnt[v] = 0;
    __syncthreads();
    for (int e = t; e < N_EDGES; e += 512) atomicAdd(&s_cnt[dst[e]], 1);
    __syncthreads();

    // 3-to-1 block sums, Hillis-Steele over 256, expand back
    if (t < 256) s_blk[t] = s_cnt[3 * t] + s_cnt[3 * t + 1] + s_cnt[3 * t + 2];
    __syncthreads();
    for (int o = 1; o < 256; o <<= 1) {
        int v = 0;
        if (t < 256 && t >= o) v = s_blk[t - o];
        __syncthreads();
        if (t < 256 && t >= o) s_blk[t] += v;
        __syncthreads();
    }
    if (t < 256) {
        int a0 = s_cnt[3 * t], a1 = s_cnt[3 * t + 1], a2 = s_cnt[3 * t + 2];
        int excl = s_blk[t] - (a0 + a1 + a2);
        s_off[3 * t] = excl;
        s_off[3 * t + 1] = excl + a0;
        s_off[3 * t + 2] = excl + a0 + a1;
    }
    __syncthreads();
    for (int v = t; v < N_NODES; v += 512) {
        float di = 1.0f / sqrtf((float)(s_cnt[v] + 1));   // +1 self-loop
        s_dinv[v] = di;
        dinv_g[v] = di;
        cnt_g[v] = s_cnt[v];
        off_g[v] = s_off[v];
    }
    __syncthreads();
    // scatter (mutates s_off as cursor; global off already written)
    for (int e = t; e < N_EDGES; e += 512) {
        int d = dst[e], sI = src[e];
        int p = atomicAdd(&s_off[d], 1);
        csr_src[p] = sI;
        csr_w[p] = s_dinv[sI] * s_dinv[d];
    }
}

// ---------------- layer1: h1 = elu( (A x) Wc1 + bc1 ) ----------------
__global__ __launch_bounds__(256) void k_layer1(
    const float* __restrict__ x, const float* __restrict__ Wc1,
    const float* __restrict__ bc1, const int* __restrict__ off,
    const int* __restrict__ cnt, const float* __restrict__ dinv,
    const int* __restrict__ csr_src, const float* __restrict__ csr_w,
    float* __restrict__ h1) {
    int v = blockIdx.x;
    int t = threadIdx.x;
    __shared__ float agg6[D_INF];
    int base = off[v], c = cnt[v];
    float dv = dinv[v];
    if (t < 64) {   // one wave aggregates x
        float a[D_INF] = {0.f, 0.f, 0.f, 0.f, 0.f, 0.f};
        if (t == 0) {
            float w = dv * dv;     // self-loop
            #pragma unroll
            for (int k = 0; k < D_INF; ++k) a[k] = w * x[v * D_INF + k];
        }
        #pragma unroll 4
        for (int n = t; n < c; n += 64) {
            int s = csr_src[base + n];
            float w = csr_w[base + n];
            #pragma unroll
            for (int k = 0; k < D_INF; ++k) a[k] = fmaf(w, x[s * D_INF + k], a[k]);
        }
        #pragma unroll
        for (int m = 32; m >= 1; m >>= 1) {
            #pragma unroll
            for (int k = 0; k < D_INF; ++k) a[k] += __shfl_xor(a[k], m, 64);
        }
        if (t == 0) {
            #pragma unroll
            for (int k = 0; k < D_INF; ++k) agg6[k] = a[k];
        }
    }
    __syncthreads();
    float acc = bc1[t];
    #pragma unroll
    for (int k = 0; k < D_INF; ++k) acc = fmaf(agg6[k], Wc1[k * H + t], acc);
    h1[v * H + t] = (acc > 0.f) ? acc : expm1f(acc);   // elu
}

// ---------------- fused: agg -> h2 -> ai/ajc for RO=3 rows per 512-thread block ----
__global__ __launch_bounds__(512) void k_out(
    const float* __restrict__ h1, const float* __restrict__ Wc2,
    const float* __restrict__ bc2, const float* __restrict__ We1,
    const float* __restrict__ be1, const int* __restrict__ off,
    const int* __restrict__ cnt, const float* __restrict__ dinv,
    const int* __restrict__ csr_src, const float* __restrict__ csr_w,
    float* __restrict__ aib, float* __restrict__ ajc) {
    int t = threadIdx.x;
    int tc = t & 255, th = t >> 8;
    int v0 = blockIdx.x * RO;
    __shared__ float s_agg[RO][H];
    __shared__ float s_h2[RO][H];

    // stage 1: aggregate h1 for 3 rows (rows 0,1 in parallel halves; row 2 by half 0)
    #pragma unroll
    for (int pass = 0; pass < 2; ++pass) {
        int r = (pass == 0) ? th : 2;
        if (pass == 0 || th == 0) {
            int v = v0 + r;
            int base = off[v], c = cnt[v];
            float dv = dinv[v];
            float acc = dv * dv * h1[v * H + tc];   // self-loop
            #pragma unroll 4
            for (int n = 0; n < c; ++n) {
                int s = csr_src[base + n];
                acc = fmaf(csr_w[base + n], h1[s * H + tc], acc);
            }
            s_agg[r][tc] = acc;
        }
    }
    __syncthreads();

    // stage 2: h2 = agg @ Wc2 + bc2.  half0: rows 0 & 2, half1: row 1 (row2 redundant)
    int r0 = (th == 0) ? 0 : 1;
    float h2a = bc2[tc], h2b = bc2[tc];
    #pragma unroll 8
    for (int k = 0; k < H; ++k) {
        float w = Wc2[k * H + tc];
        h2a = fmaf(s_agg[r0][k], w, h2a);
        h2b = fmaf(s_agg[2][k], w, h2b);
    }
    s_h2[r0][tc] = h2a;
    if (th == 0) s_h2[2][tc] = h2b;
    __syncthreads();

    // stage 3: half0 -> ai = h2 @ We1[:H]; half1 -> ajc = h2 @ We1[H:] + be1
    const float* wp = We1 + (size_t)(th * H) * H + tc;
    float a0 = 0.f, a1 = 0.f, a2 = 0.f;
    #pragma unroll 8
    for (int m = 0; m < H; ++m) {
        float w = wp[(size_t)m * H];
        a0 = fmaf(s_h2[0][m], w, a0);
        a1 = fmaf(s_h2[1][m], w, a1);
        a2 = fmaf(s_h2[2][m], w, a2);
    }
    float* o = (th == 0) ? aib : ajc;
    float bb = (th == 0) ? 0.f : be1[tc];
    o[(v0 + 0) * H + tc] = a0 + bb;
    o[(v0 + 1) * H + tc] = a1 + bb;
    o[(v0 + 2) * H + tc] = a2 + bb;
}

// ---------------- pair + fused row softmax ----------------
// logits[i,j] = sum_h relu(ai[i,h] + ajc[j,h]) * w2[h]   (be2/temp dropped: softmax-invariant)
__global__ __launch_bounds__(256) void k_pair(
    const float* __restrict__ aib, const float* __restrict__ ajc,
    const float* __restrict__ We2, float* __restrict__ out) {
    int t = threadIdx.x;
    int i0 = blockIdx.x * TI;
    __shared__ __align__(16) float s_ai[TI][H];
    __shared__ __align__(16) float s_w2[H];
    __shared__ float red[TI][256];

    s_w2[t] = We2[t];
    #pragma unroll
    for (int i = 0; i < TI; ++i) s_ai[i][t] = aib[(i0 + i) * H + t];
    __syncthreads();

    float acc[TI][3];
    #pragma unroll
    for (int i = 0; i < TI; ++i)
        #pragma unroll
        for (int jj = 0; jj < 3; ++jj) acc[i][jj] = 0.f;

    const float4* A0 = (const float4*)(ajc + (size_t)(t)       * H);
    const float4* A1 = (const float4*)(ajc + (size_t)(t + 256) * H);
    const float4* A2 = (const float4*)(ajc + (size_t)(t + 512) * H);

    #pragma unroll 4
    for (int h4 = 0; h4 < H / 4; ++h4) {
        float4 w = *(const float4*)&s_w2[h4 * 4];
        float4 av0 = *(const float4*)&s_ai[0][h4 * 4];
        float4 av1 = *(const float4*)&s_ai[1][h4 * 4];
        float4 av2 = *(const float4*)&s_ai[2][h4 * 4];
        float4 b0 = A0[h4], b1 = A1[h4], b2 = A2[h4];
        #define STEP(AV, I)                                                    \
            acc[I][0] = fmaf(fmaxf(AV.x + b0.x, 0.f), w.x, acc[I][0]);         \
            acc[I][0] = fmaf(fmaxf(AV.y + b0.y, 0.f), w.y, acc[I][0]);         \
            acc[I][0] = fmaf(fmaxf(AV.z + b0.z, 0.f), w.z, acc[I][0]);         \
            acc[I][0] = fmaf(fmaxf(AV.w + b0.w, 0.f), w.w, acc[I][0]);         \
            acc[I][1] = fmaf(fmaxf(AV.x + b1.x, 0.f), w.x, acc[I][1]);         \
            acc[I][1] = fmaf(fmaxf(AV.y + b1.y, 0.f), w.y, acc[I][1]);         \
            acc[I][1] = fmaf(fmaxf(AV.z + b1.z, 0.f), w.z, acc[I][1]);         \
            acc[I][1] = fmaf(fmaxf(AV.w + b1.w, 0.f), w.w, acc[I][1]);         \
            acc[I][2] = fmaf(fmaxf(AV.x + b2.x, 0.f), w.x, acc[I][2]);         \
            acc[I][2] = fmaf(fmaxf(AV.y + b2.y, 0.f), w.y, acc[I][2]);         \
            acc[I][2] = fmaf(fmaxf(AV.z + b2.z, 0.f), w.z, acc[I][2]);         \
            acc[I][2] = fmaf(fmaxf(AV.w + b2.w, 0.f), w.w, acc[I][2]);
        STEP(av0, 0)
        STEP(av1, 1)
        STEP(av2, 2)
        #undef STEP
    }

    // mask diagonal
    #pragma unroll
    for (int i = 0; i < TI; ++i) {
        int row = i0 + i;
        #pragma unroll
        for (int jj = 0; jj < 3; ++jj)
            if (t + jj * 256 == row) acc[i][jj] = -INFINITY;
    }

    // row max
    #pragma unroll
    for (int i = 0; i < TI; ++i)
        red[i][t] = fmaxf(fmaxf(acc[i][0], acc[i][1]), acc[i][2]);
    __syncthreads();
    for (int s = 128; s > 0; s >>= 1) {
        if (t < s) {
            #pragma unroll
            for (int i = 0; i < TI; ++i)
                red[i][t] = fmaxf(red[i][t], red[i][t + s]);
        }
        __syncthreads();
    }
    float mx[TI];
    #pragma unroll
    for (int i = 0; i < TI; ++i) mx[i] = red[i][0];
    __syncthreads();

    // exp + row sum
    float e[TI][3];
    #pragma unroll
    for (int i = 0; i < TI; ++i) {
        float s0 = 0.f;
        #pragma unroll
        for (int jj = 0; jj < 3; ++jj) {
            e[i][jj] = __expf(acc[i][jj] - mx[i]);
            s0 += e[i][jj];
        }
        red[i][t] = s0;
    }
    __syncthreads();
    for (int s = 128; s > 0; s >>= 1) {
        if (t < s) {
            #pragma unroll
            for (int i = 0; i < TI; ++i)
                red[i][t] += red[i][t + s];
        }
        __syncthreads();
    }
    #pragma unroll
    for (int i = 0; i < TI; ++i) {
        float inv = 1.0f / red[i][0];
        #pragma unroll
        for (int jj = 0; jj < 3; ++jj)
            out[(size_t)(i0 + i) * N_NODES + t + jj * 256] = e[i][jj] * inv;
    }
}

extern "C" void kernel_launch(void* const* d_in, const int* in_sizes, int n_in,
                              void* d_out, int out_size, void* d_ws, size_t ws_size,
                              hipStream_t stream) {
    const float* x   = (const float*)d_in[0];
    const int*   ei  = (const int*)d_in[1];
    const float* Wc1 = (const float*)d_in[2];
    const float* bc1 = (const float*)d_in[3];
    const float* Wc2 = (const float*)d_in[4];
    const float* bc2 = (const float*)d_in[5];
    const float* We1 = (const float*)d_in[6];
    const float* be1 = (const float*)d_in[7];
    const float* We2 = (const float*)d_in[8];
    // be2 (d_in[9]) intentionally unused: softmax is shift-invariant.
    float* out = (float*)d_out;

    char* ws = (char*)d_ws;
    int*   cnt     = (int*)(ws + 0);
    int*   off     = (int*)(ws + 3072);
    float* dinv    = (float*)(ws + 6144);
    int*   csr_src = (int*)(ws + 9216);
    float* csr_w   = (float*)(ws + 58368);
    float* h1      = (float*)(ws + 107520);
    float* aib     = (float*)(ws + 893952);
    float* ajc     = (float*)(ws + 1680384);

    const int* srcA = ei;             // edge_index[0]
    const int* dstA = ei + N_EDGES;   // edge_index[1]

    k_prep<<<1, 512, 0, stream>>>(srcA, dstA, cnt, off, dinv, csr_src, csr_w);
    k_layer1<<<N_NODES, 256, 0, stream>>>(x, Wc1, bc1, off, cnt, dinv, csr_src, csr_w, h1);
    k_out<<<N_NODES / RO, 512, 0, stream>>>(h1, Wc2, bc2, We1, be1, off, cnt, dinv,
                                            csr_src, csr_w, aib, ajc);
    k_pair<<<N_NODES / TI, 256, 0, stream>>>(aib, ajc, We2, out);
}